// Round 6
// baseline (379.440 us; speedup 1.0000x reference)
//
#include <hip/hip_runtime.h>

static constexpr int   N_DIM        = 64;
static constexpr float HALF_LOG_2PI = 0.9189385332046727f;
static constexpr float CLIP_RATIO   = 0.2f;
static constexpr float DUAL_CLIP    = 5.0f;
static constexpr int   GRID         = 2048;   // main-kernel blocks
static constexpr float ENT_CONST    = (float)N_DIM * (0.5f + HALF_LOG_2PI); // per-row entropy const
static constexpr float ENT_C16      = ENT_CONST / 16.0f;  // spread over 16 lanes

// clang ext-vector so __builtin_nontemporal_load works (HIP float4 is a
// struct, not a vector type). .x/.y/.z/.w swizzles are native.
using f4 = __attribute__((ext_vector_type(4))) float;

// ROUND-5 POST-MORTEM: all-nt loads -> 88->58.4 us, delivered 5.86 TB/s =
// 93% of the 6.29 TB/s measured-achievable ceiling. FETCH_SIZE unchanged
// across ALL rounds (167 MB): nt never changed the L3 hit mix — it removed
// allocation/replacement churn in the cache pipeline (cached=2.9,
// partial-nt=3.86, all-nt=5.86 TB/s at identical hit rate). The main kernel
// is at the bandwidth wall: 341 MB mandatory / 6.29 TB/s = 54.2 us floor,
// 58.4 measured. This round fuses the reduce kernel (launch + ws round-trip
// removal) — the last non-roofline cost in the pipeline.
__device__ __forceinline__ f4 ld_nt(const float* p)
{
    return __builtin_nontemporal_load((const f4*)p);
}

// Per-lane partials for one 4-row set (lane group of 16 covers one row's 64
// dims as 4 elems/lane). en = sum log(sigma_new) partial; d = partial of
// (logp_new - logp_old) (HALF_LOG_2PI cancels).
// Trans-op diet: log of the 4-element product (sigma in [0.5,1.5] -> product
// in [0.0625, 5.06], no over/underflow): 2 logs instead of 8 per set.
__device__ __forceinline__ void ppo_set(const f4& mn, const f4& sn,
                                        const f4& mo, const f4& so,
                                        const f4& a,
                                        float& en_out, float& d_out)
{
    float qn = 0.f, qo = 0.f;
    float pn = 1.f, po = 1.f;
#define PPO_COMP(c) {                                        \
        float rn = __builtin_amdgcn_rcpf(sn.c);              \
        float zn = (a.c - mn.c) * rn;  qn += zn * zn;        \
        float ro = __builtin_amdgcn_rcpf(so.c);              \
        float zo = (a.c - mo.c) * ro;  qo += zo * zo;        \
        pn *= sn.c;  po *= so.c; }
    PPO_COMP(x) PPO_COMP(y) PPO_COMP(z) PPO_COMP(w)
#undef PPO_COMP
    const float en = __logf(pn);
    const float eo = __logf(po);
    en_out = en;
    d_out  = 0.5f * (qo - qn) + (eo - en);   // pn - po, per-lane partial
}

// Reduction + scalar tail for one set. accK/accE take per-lane partials
// (pre-reduce, linear). Only d crosses lanes (feeds exp). Tail runs
// redundantly on all 16 lanes of a row group (exact 16x, scaled 1/16 later).
__device__ __forceinline__ void ppo_tail(float en, float d, float w, float ad,
                                         float& accP, float& accE,
                                         float& accK, float& accC)
{
    accK -= d;                       // approx_kl partial (pre-reduce)
    accE += w * (en + ENT_C16);      // entropy partial
#pragma unroll
    for (int m = 1; m < 16; m <<= 1) d += __shfl_xor(d, m, 16);
    const float ratio = __expf(d);
    const float rc = fminf(fmaxf(ratio, 1.f - CLIP_RATIO), 1.f + CLIP_RATIO);
    float cl = fminf(ratio * ad, rc * ad);
    cl = fmaxf(cl, DUAL_CLIP * ad);
    accP += cl * w;
    accC += (fabsf(ratio - 1.f) > CLIP_RATIO) ? 1.f : 0.f;
}

// ---------------------------------------------------------------------------
// Main kernel — round-5 streaming structure (untouched) + fused finalize.
// Per-block partials go to 5 fp64 accumulators in ws via device-scope
// atomics (one atomic per block per accumulator — contention-minimal; each
// slot on its own 64 B line so the 5 streams of 2048 ops pipeline through
// different L2 banks). fp64 accumulation makes the nondeterministic atomic
// ordering invisible at fp32 output precision. The last block to finish
// (atomic counter, post-threadfence) reads the totals back with
// atomicAdd(+0.0) (coherent by construction) and writes the 5 outputs.
// ws is zeroed each replay by a 384 B hipMemsetAsync before the kernel.
// ---------------------------------------------------------------------------
__global__ __launch_bounds__(256) void ppo_main(
    const float* __restrict__ mu_new,
    const float* __restrict__ sg_new,
    const float* __restrict__ mu_old,
    const float* __restrict__ sg_old,
    const float* __restrict__ act,
    const float* __restrict__ vnew,
    const float* __restrict__ vold,
    const float* __restrict__ adv,
    const float* __restrict__ ret,
    const float* __restrict__ wgt,
    double* __restrict__ ws,          // 5 x 64B-padded fp64 slots + counter
    float* __restrict__ out,
    int b_rows)
{
    const int t    = threadIdx.x;
    const int wave = t >> 6;        // 4 waves/block
    const int lane = t & 63;
    const int sub  = lane >> 4;     // row within a 4-row set

    float accP = 0.f, accV = 0.f, accE = 0.f, accK = 0.f, accC = 0.f;

    // ---- value-loss pass: one row per thread, coalesced, no divergence ----
    {
        const int r = blockIdx.x * 256 + t;
        if (r < b_rows) {
            const float vn = vnew[r], vo = vold[r], rt = ret[r], w = wgt[r];
            const float vc = vo + fminf(fmaxf(vn - vo, -CLIP_RATIO), CLIP_RATIO);
            const float d1 = rt - vn, d2 = rt - vc;
            accV += fmaxf(d1 * d1, d2 * d2) * w;
        }
    }

    // ---- policy / entropy / kl / clipfrac: 32 rows per block-step ----
    const int n_g = b_rows >> 5;
    for (int g = blockIdx.x; g < n_g; g += gridDim.x) {
        const int row0 = g * 32 + wave * 8;          // first of this wave's 8 rows
        const int r0   = row0 + sub;                 // set-0 row for this lane
        const int r1   = r0 + 4;                     // set-1 row
        const int off0 = row0 * N_DIM + lane * 4;
        const int off1 = off0 + 4 * N_DIM;

        // issue all 10 vector loads + 4 broadcast scalars before any use
        const f4 mn0 = ld_nt(mu_new + off0);
        const f4 sn0 = ld_nt(sg_new + off0);
        const f4 mo0 = ld_nt(mu_old + off0);
        const f4 so0 = ld_nt(sg_old + off0);
        const f4 a0  = ld_nt(act    + off0);
        const f4 mn1 = ld_nt(mu_new + off1);
        const f4 sn1 = ld_nt(sg_new + off1);
        const f4 mo1 = ld_nt(mu_old + off1);
        const f4 so1 = ld_nt(sg_old + off1);
        const f4 a1  = ld_nt(act    + off1);
        const float w0 = wgt[r0], ad0 = adv[r0];
        const float w1 = wgt[r1], ad1 = adv[r1];

        float en0, d0, en1, d1;
        ppo_set(mn0, sn0, mo0, so0, a0, en0, d0);
        ppo_set(mn1, sn1, mo1, so1, a1, en1, d1);

        ppo_tail(en0, d0, w0, ad0, accP, accE, accK, accC);
        ppo_tail(en1, d1, w1, ad1, accP, accE, accK, accC);
    }

    accP *= 0.0625f;   // undo 16x redundancy (exact: power of 2)
    accC *= 0.0625f;

    // full-wave butterfly for all 5 accumulators
#pragma unroll
    for (int m = 1; m < 64; m <<= 1) {
        accP += __shfl_xor(accP, m, 64);
        accV += __shfl_xor(accV, m, 64);
        accE += __shfl_xor(accE, m, 64);
        accK += __shfl_xor(accK, m, 64);
        accC += __shfl_xor(accC, m, 64);
    }

    __shared__ float red[4][5];
    if (lane == 0) {
        red[wave][0] = accP; red[wave][1] = accV; red[wave][2] = accE;
        red[wave][3] = accK; red[wave][4] = accC;
    }
    __syncthreads();

    if (t == 0) {
        float s[5] = {0.f, 0.f, 0.f, 0.f, 0.f};
#pragma unroll
        for (int wv = 0; wv < 4; ++wv)
#pragma unroll
            for (int k = 0; k < 5; ++k) s[k] += red[wv][k];

        // one fp64 atomic per accumulator; slot k at double-index 8k = 64 B apart
#pragma unroll
        for (int k = 0; k < 5; ++k)
            atomicAdd(&ws[k * 8], (double)s[k]);

        __threadfence();   // slot-atomics globally visible before the ticket
        unsigned* ctr = (unsigned*)(ws + 40);          // byte offset 320
        const unsigned old = atomicAdd(ctr, 1u);
        if (old == (unsigned)gridDim.x - 1u) {
            // last block: coherent read-back via atomic(+0.0), finalize
            const double tP = atomicAdd(&ws[0],  0.0);
            const double tV = atomicAdd(&ws[8],  0.0);
            const double tE = atomicAdd(&ws[16], 0.0);
            const double tK = atomicAdd(&ws[24], 0.0);
            const double tC = atomicAdd(&ws[32], 0.0);
            const double invB = 1.0 / (double)b_rows;
            out[0] = (float)(-tP * invB);        // policy_loss
            out[1] = (float)(0.5 * tV * invB);   // value_loss
            out[2] = (float)(tE * invB);         // entropy_loss
            out[3] = (float)(tK * invB);         // approx_kl
            out[4] = (float)(tC * invB);         // clipfrac
        }
    }
}

extern "C" void kernel_launch(void* const* d_in, const int* in_sizes, int n_in,
                              void* d_out, int out_size, void* d_ws, size_t ws_size,
                              hipStream_t stream) {
    const float* mu_new = (const float*)d_in[0];
    const float* sg_new = (const float*)d_in[1];
    const float* mu_old = (const float*)d_in[2];
    const float* sg_old = (const float*)d_in[3];
    const float* act    = (const float*)d_in[4];
    const float* vnew   = (const float*)d_in[5];
    const float* vold   = (const float*)d_in[6];
    const float* adv    = (const float*)d_in[7];
    const float* ret    = (const float*)d_in[8];
    const float* wgt    = (const float*)d_in[9];
    float* out = (float*)d_out;
    double* ws = (double*)d_ws;

    const int b_rows = in_sizes[5];     // B from value_new

    // zero the 5 fp64 slots + ticket counter (384 B); stream-ordered,
    // graph-capture legal, runs each replay.
    hipMemsetAsync(d_ws, 0, 384, stream);

    ppo_main<<<GRID, 256, 0, stream>>>(mu_new, sg_new, mu_old, sg_old, act,
                                       vnew, vold, adv, ret, wgt,
                                       ws, out, b_rows);
}

// Round 7
// 285.613 us; speedup vs baseline: 1.3285x; 1.3285x over previous
//
#include <hip/hip_runtime.h>

static constexpr int   N_DIM        = 64;
static constexpr float HALF_LOG_2PI = 0.9189385332046727f;
static constexpr float CLIP_RATIO   = 0.2f;
static constexpr float DUAL_CLIP    = 5.0f;
static constexpr int   GRID         = 2048;   // main-kernel blocks
static constexpr float ENT_CONST    = (float)N_DIM * (0.5f + HALF_LOG_2PI); // per-row entropy const
static constexpr float ENT_C16      = ENT_CONST / 16.0f;  // spread over 16 lanes

// clang ext-vector so __builtin_nontemporal_load works (HIP float4 is a
// struct, not a vector type). .x/.y/.z/.w swizzles are native.
using f4 = __attribute__((ext_vector_type(4))) float;

// ROUND-5/6 POST-MORTEM (final state): all-nt loads give 5.86 TB/s delivered
// = 93% of the 6.29 TB/s measured copy ceiling (cached=2.9, partial-nt=3.86,
// all-nt=5.86 at IDENTICAL 167 MB FETCH_SIZE -> the nt cpol removes L3
// allocation/replacement churn, not hits; memory-side cache, hits add no BW).
// Round 6 tried fusing the reduce via device-scope fp64 atomics + threadfence:
// ppo_main 58->163 us — per-block agent-scope release forces L2
// writeback/invalidate across 8 non-coherent XCD L2s, throttling the whole
// stream (5.86->2.1 TB/s, FETCH unchanged). REVERTED to the two-kernel form.
// Structural floor: 341 MB mandatory fp32 traffic / 6.29 TB/s = 54.2 us;
// this kernel measures 58.4 us (93%). Roofline.
__device__ __forceinline__ f4 ld_nt(const float* p)
{
    return __builtin_nontemporal_load((const f4*)p);
}

// Per-lane partials for one 4-row set (lane group of 16 covers one row's 64
// dims as 4 elems/lane). en = sum log(sigma_new) partial; d = partial of
// (logp_new - logp_old) (HALF_LOG_2PI cancels).
// Trans-op diet: log of the 4-element product (sigma in [0.5,1.5] -> product
// in [0.0625, 5.06], no over/underflow): 2 logs instead of 8 per set.
__device__ __forceinline__ void ppo_set(const f4& mn, const f4& sn,
                                        const f4& mo, const f4& so,
                                        const f4& a,
                                        float& en_out, float& d_out)
{
    float qn = 0.f, qo = 0.f;
    float pn = 1.f, po = 1.f;
#define PPO_COMP(c) {                                        \
        float rn = __builtin_amdgcn_rcpf(sn.c);              \
        float zn = (a.c - mn.c) * rn;  qn += zn * zn;        \
        float ro = __builtin_amdgcn_rcpf(so.c);              \
        float zo = (a.c - mo.c) * ro;  qo += zo * zo;        \
        pn *= sn.c;  po *= so.c; }
    PPO_COMP(x) PPO_COMP(y) PPO_COMP(z) PPO_COMP(w)
#undef PPO_COMP
    const float en = __logf(pn);
    const float eo = __logf(po);
    en_out = en;
    d_out  = 0.5f * (qo - qn) + (eo - en);   // pn - po, per-lane partial
}

// Reduction + scalar tail for one set. accK/accE take per-lane partials
// (pre-reduce, linear). Only d crosses lanes (feeds exp). Tail runs
// redundantly on all 16 lanes of a row group (exact 16x, scaled 1/16 later).
__device__ __forceinline__ void ppo_tail(float en, float d, float w, float ad,
                                         float& accP, float& accE,
                                         float& accK, float& accC)
{
    accK -= d;                       // approx_kl partial (pre-reduce)
    accE += w * (en + ENT_C16);      // entropy partial
#pragma unroll
    for (int m = 1; m < 16; m <<= 1) d += __shfl_xor(d, m, 16);
    const float ratio = __expf(d);
    const float rc = fminf(fmaxf(ratio, 1.f - CLIP_RATIO), 1.f + CLIP_RATIO);
    float cl = fminf(ratio * ad, rc * ad);
    cl = fmaxf(cl, DUAL_CLIP * ad);
    accP += cl * w;
    accC += (fabsf(ratio - 1.f) > CLIP_RATIO) ? 1.f : 0.f;
}

// ---------------------------------------------------------------------------
// Main kernel. Round-5 streaming structure: 8 rows per wave-step, all five
// big streams non-temporal, per-block partials to ws (plain stores, no
// atomics, no fences — see post-mortem above for why).
// ---------------------------------------------------------------------------
__global__ __launch_bounds__(256) void ppo_main(
    const float* __restrict__ mu_new,
    const float* __restrict__ sg_new,
    const float* __restrict__ mu_old,
    const float* __restrict__ sg_old,
    const float* __restrict__ act,
    const float* __restrict__ vnew,
    const float* __restrict__ vold,
    const float* __restrict__ adv,
    const float* __restrict__ ret,
    const float* __restrict__ wgt,
    float* __restrict__ ws,
    int b_rows)
{
    const int t    = threadIdx.x;
    const int wave = t >> 6;        // 4 waves/block
    const int lane = t & 63;
    const int sub  = lane >> 4;     // row within a 4-row set

    float accP = 0.f, accV = 0.f, accE = 0.f, accK = 0.f, accC = 0.f;

    // ---- value-loss pass: one row per thread, coalesced, no divergence ----
    {
        const int r = blockIdx.x * 256 + t;
        if (r < b_rows) {
            const float vn = vnew[r], vo = vold[r], rt = ret[r], w = wgt[r];
            const float vc = vo + fminf(fmaxf(vn - vo, -CLIP_RATIO), CLIP_RATIO);
            const float d1 = rt - vn, d2 = rt - vc;
            accV += fmaxf(d1 * d1, d2 * d2) * w;
        }
    }

    // ---- policy / entropy / kl / clipfrac: 32 rows per block-step ----
    const int n_g = b_rows >> 5;
    for (int g = blockIdx.x; g < n_g; g += gridDim.x) {
        const int row0 = g * 32 + wave * 8;          // first of this wave's 8 rows
        const int r0   = row0 + sub;                 // set-0 row for this lane
        const int r1   = r0 + 4;                     // set-1 row
        const int off0 = row0 * N_DIM + lane * 4;
        const int off1 = off0 + 4 * N_DIM;

        // issue all 10 vector loads + 4 broadcast scalars before any use
        const f4 mn0 = ld_nt(mu_new + off0);
        const f4 sn0 = ld_nt(sg_new + off0);
        const f4 mo0 = ld_nt(mu_old + off0);
        const f4 so0 = ld_nt(sg_old + off0);
        const f4 a0  = ld_nt(act    + off0);
        const f4 mn1 = ld_nt(mu_new + off1);
        const f4 sn1 = ld_nt(sg_new + off1);
        const f4 mo1 = ld_nt(mu_old + off1);
        const f4 so1 = ld_nt(sg_old + off1);
        const f4 a1  = ld_nt(act    + off1);
        const float w0 = wgt[r0], ad0 = adv[r0];
        const float w1 = wgt[r1], ad1 = adv[r1];

        float en0, d0, en1, d1;
        ppo_set(mn0, sn0, mo0, so0, a0, en0, d0);
        ppo_set(mn1, sn1, mo1, so1, a1, en1, d1);

        ppo_tail(en0, d0, w0, ad0, accP, accE, accK, accC);
        ppo_tail(en1, d1, w1, ad1, accP, accE, accK, accC);
    }

    accP *= 0.0625f;   // undo 16x redundancy (exact: power of 2)
    accC *= 0.0625f;

    // full-wave butterfly for all 5 accumulators
#pragma unroll
    for (int m = 1; m < 64; m <<= 1) {
        accP += __shfl_xor(accP, m, 64);
        accV += __shfl_xor(accV, m, 64);
        accE += __shfl_xor(accE, m, 64);
        accK += __shfl_xor(accK, m, 64);
        accC += __shfl_xor(accC, m, 64);
    }

    __shared__ float red[4][5];
    if (lane == 0) {
        red[wave][0] = accP; red[wave][1] = accV; red[wave][2] = accE;
        red[wave][3] = accK; red[wave][4] = accC;
    }
    __syncthreads();

    if (t == 0) {
        float s[5] = {0.f, 0.f, 0.f, 0.f, 0.f};
#pragma unroll
        for (int wv = 0; wv < 4; ++wv)
#pragma unroll
            for (int k = 0; k < 5; ++k) s[k] += red[wv][k];
        // column-major so the reduce kernel reads coalesced
#pragma unroll
        for (int k = 0; k < 5; ++k) ws[k * GRID + blockIdx.x] = s[k];
    }
}

// ---------------------------------------------------------------------------
// Final reduce: 5 waves, one output each — no syncthreads, no atomics.
// ---------------------------------------------------------------------------
__global__ __launch_bounds__(320) void ppo_reduce(
    const float* __restrict__ ws, float* __restrict__ out, int b_rows)
{
    const int wave = threadIdx.x >> 6;   // 0..4 -> output index
    const int lane = threadIdx.x & 63;

    float v = 0.f;
    for (int i = lane; i < GRID; i += 64) v += ws[wave * GRID + i];
#pragma unroll
    for (int m = 1; m < 64; m <<= 1) v += __shfl_xor(v, m, 64);

    if (lane == 0) {
        const float invB = 1.0f / (float)b_rows;
        float o;
        if      (wave == 0) o = -v * invB;        // policy_loss
        else if (wave == 1) o = 0.5f * v * invB;  // value_loss
        else                o = v * invB;         // entropy / kl / clipfrac
        out[wave] = o;
    }
}

extern "C" void kernel_launch(void* const* d_in, const int* in_sizes, int n_in,
                              void* d_out, int out_size, void* d_ws, size_t ws_size,
                              hipStream_t stream) {
    const float* mu_new = (const float*)d_in[0];
    const float* sg_new = (const float*)d_in[1];
    const float* mu_old = (const float*)d_in[2];
    const float* sg_old = (const float*)d_in[3];
    const float* act    = (const float*)d_in[4];
    const float* vnew   = (const float*)d_in[5];
    const float* vold   = (const float*)d_in[6];
    const float* adv    = (const float*)d_in[7];
    const float* ret    = (const float*)d_in[8];
    const float* wgt    = (const float*)d_in[9];
    float* out = (float*)d_out;
    float* ws  = (float*)d_ws;

    const int b_rows = in_sizes[5];     // B from value_new

    ppo_main<<<GRID, 256, 0, stream>>>(mu_new, sg_new, mu_old, sg_old, act,
                                       vnew, vold, adv, ret, wgt,
                                       ws, b_rows);
    ppo_reduce<<<1, 320, 0, stream>>>(ws, out, b_rows);
}